// Round 9
// baseline (692.227 us; speedup 1.0000x reference)
//
#include <hip/hip_runtime.h>
#include <hip/hip_bf16.h>

typedef unsigned short u16;
typedef unsigned int u32;

constexpr int NN = 50000;   // nodes
constexpr int NE = 400000;  // edges
constexpr int MPAD = 50048; // 782 * 64 row-padded M

typedef __attribute__((ext_vector_type(8))) short s16x8;
typedef __attribute__((ext_vector_type(4))) float f32x4;

__device__ __forceinline__ float bf2f(u16 u) {
    union { u32 i; float f; } v; v.i = ((u32)u) << 16; return v.f;
}
__device__ __forceinline__ u16 f2bf(float f) {
    union { float f; u32 i; } v; v.f = f;
    u32 r = v.i + 0x7fffu + ((v.i >> 16) & 1u);
    return (u16)(r >> 16);
}
// dtype-adaptive float load: isbf=1 -> bf16 storage, isbf=0 -> f32 storage
__device__ __forceinline__ float ldf(const void* p, size_t i, int isbf) {
    if (isbf) return bf2f(((const u16*)p)[i]);
    return ((const float*)p)[i];
}
__device__ __forceinline__ float clampf(float v) {
    // kills inf AND NaN (fmaxf(NaN,x)=x on HIP); never binds for sane values
    return fminf(fmaxf(v, -1e4f), 1e4f);
}
// order-preserving f32 <-> u32 encode for atomicMax (no NaN inputs: clampf'd)
__device__ __forceinline__ u32 menc(float f) {
    union { float f; u32 i; } v; v.f = f;
    return (v.i & 0x80000000u) ? ~v.i : (v.i | 0x80000000u);
}
__device__ __forceinline__ float mdec(u32 k) {
    if (k == 0u) return 0.f;                      // unwritten (deg==0)
    union { u32 i; float f; } v;
    v.i = (k & 0x80000000u) ? (k & 0x7fffffffu) : ~k;
    return v.f;
}

// ---------------- static device scratch (independent of d_ws) ----------------
__device__ int   g_flag;
__device__ int   g_counter;
__device__ float g_qe1[256], g_qe2[256];
__device__ float g_eq1[16], g_eq2[16];
__device__ float g_ps1[128], g_pd1[128], g_ps2[512], g_pd2[512];
__device__ float g_bnsum[128], g_bnsumsq[128], g_bnscale[128], g_bnshift[128];
__device__ int   g_deg[NN], g_start[NN], g_cur[NN];
__device__ int   g_slot[NE];                      // edge -> CSR slot
__device__ int   g_srccsr[NE];                    // CSR-ordered src index
__device__ u32   g_mkey[NN * 4];                  // per (dst,head) max (encoded)
__device__ __attribute__((aligned(16))) float g_sbuf[NN * 4];
__device__ __attribute__((aligned(16))) float g_dbuf[NN * 4];
__device__ __attribute__((aligned(16))) float g_alpha[(size_t)NE * 4];  // raw el1
__device__ __attribute__((aligned(16))) float g_el2[(size_t)NE * 4];    // raw el2
__device__ __attribute__((aligned(16))) float g_acsr[(size_t)NE * 4];   // CSR alpha
__device__ __attribute__((aligned(16))) float g_xbuf[(size_t)NN * 128];
__device__ __attribute__((aligned(16))) float g_acc2[(size_t)NN * 128];
// MFMA GEMM operands (bf16). A rows padded to MPAD; B stored K-major (Bt[j][k]).
__device__ __attribute__((aligned(16))) u16 g_A1[(size_t)MPAD * 64];
__device__ __attribute__((aligned(16))) u16 g_A2[(size_t)MPAD * 160];
__device__ __attribute__((aligned(16))) u16 g_B1t[192 * 64];
__device__ __attribute__((aligned(16))) u16 g_B1bt[128 * 128];
__device__ __attribute__((aligned(16))) u16 g_B2t[192 * 160];
__device__ __attribute__((aligned(16))) u16 g_B2bt[128 * 512];
// qe packed as B-matrix for edge MFMA: qeB[col][k], col 0..3=qe1 h, 4..7=qe2 h
__device__ __attribute__((aligned(16))) u16 g_qeB[16 * 64];
// per-node attention-input tables (bf16) + aggregated messages (bf16)
__device__ __attribute__((aligned(16))) u16 g_xi1[(size_t)NN * 32];
__device__ __attribute__((aligned(16))) u16 g_xi2[(size_t)NN * 128];
__device__ __attribute__((aligned(16))) u16 g_agg1[(size_t)MPAD * 128];
__device__ __attribute__((aligned(16))) u16 g_agg2[(size_t)MPAD * 512];

// ---------------- init (+ dtype detect folded in) ----------------
__global__ void k_zero(const u16* x) {
    int i = blockIdx.x * blockDim.x + threadIdx.x;
    if (i < NN) g_deg[i] = 0;
    if (i < NN * 4) g_mkey[i] = 0u;
    if (i < 128) { g_bnsum[i] = 0.f; g_bnsumsq[i] = 0.f; }
    if (i == 0) {
        int cnt = 0;
        for (int j = 0; j < 64; j++) {
            u16 u = x[2 * j];
            int ex = (u >> 7) & 0xff;
            if (ex >= 100 && ex <= 140) cnt++;
        }
        g_flag = (cnt >= 40) ? 1 : 0;
        g_counter = 0;
    }
}

// Folded projections, wave-cooperative: 16 lanes per output, 1792 outputs.
__global__ __launch_bounds__(256) void k_prep(
    const void* we1, const void* ae1, const void* we2, const void* ae2,
    const void* w1, const void* as1, const void* ad1,
    const void* w2, const void* as2, const void* ad2) {
    int isbf = g_flag;
    int t = threadIdx.x;
    int idx = blockIdx.x * 16 + (t >> 4);   // 112 blocks x 16 groups = 1792
    int s = t & 15;
    float a = 0.f;
    if (idx < 256) {                         // qe1
        int k = idx >> 2, hd = idx & 3;
        for (int c = s; c < 32; c += 16)
            a += ldf(we1, k * 128 + hd * 32 + c, isbf) * ldf(ae1, hd * 32 + c, isbf);
    } else if (idx < 512) {                  // qe2
        int i2 = idx - 256;
        int k = i2 >> 2, hd = i2 & 3;
        for (int c = s; c < 128; c += 16)
            a += ldf(we2, k * 512 + hd * 128 + c, isbf) * ldf(ae2, hd * 128 + c, isbf);
    } else if (idx < 768) {                  // ps1 / pd1
        int i2 = idx - 512;
        int isd = i2 >> 7, j = i2 & 127;
        int h = j >> 5, k = j & 31;
        const void* av = isd ? ad1 : as1;
        for (int c = s; c < 32; c += 16)
            a += ldf(w1, k * 128 + h * 32 + c, isbf) * ldf(av, h * 32 + c, isbf);
    } else {                                 // ps2 / pd2
        int i2 = idx - 768;
        int isd = i2 >> 9, j = i2 & 511;
        int h = j >> 7, k = j & 127;
        const void* av = isd ? ad2 : as2;
        for (int c = s; c < 128; c += 16)
            a += ldf(w2, (size_t)k * 512 + h * 128 + c, isbf) * ldf(av, h * 128 + c, isbf);
    }
#pragma unroll
    for (int mk = 8; mk >= 1; mk >>= 1) a += __shfl_xor(a, mk);
    if (s == 0) {
        if (idx < 256) g_qe1[idx] = a;
        else if (idx < 512) g_qe2[idx - 256] = a;
        else if (idx < 768) {
            int i2 = idx - 512;
            if (i2 >> 7) g_pd1[i2 & 127] = a; else g_ps1[i2 & 127] = a;
        } else {
            int i2 = idx - 768;
            if (i2 >> 9) g_pd2[i2 & 511] = a; else g_ps2[i2 & 511] = a;
        }
    }
}
// eq_l[et][h] = sum_k ee_l[et,k] * qe_l[k,h]; also packs g_qeB[col][k].
__global__ void k_prep2(const void* ee1, const void* ee2) {
    int isbf = g_flag;
    int t = threadIdx.x;
    int idx = blockIdx.x * 16 + (t >> 4);    // 2 blocks x 16 = 32
    int s = t & 15;
    int lyr = idx >> 4;
    int et = (idx >> 2) & 3, h = idx & 3;
    const void* ee = lyr ? ee2 : ee1;
    const float* qe = lyr ? g_qe2 : g_qe1;
    float a = 0.f;
    for (int k = s; k < 64; k += 16)
        a += ldf(ee, et * 64 + k, isbf) * qe[k * 4 + h];
#pragma unroll
    for (int mk = 8; mk >= 1; mk >>= 1) a += __shfl_xor(a, mk);
    if (s == 0) {
        if (lyr) g_eq2[et * 4 + h] = a; else g_eq1[et * 4 + h] = a;
    }
    // pack qeB: 1024 entries, 512 threads across 2 blocks -> 2 each
    int base = blockIdx.x * 256 + t;
    for (int i = base; i < 1024; i += 512) {
        int col = i >> 6, k = i & 63;
        float v = 0.f;
        if (col < 4) v = g_qe1[k * 4 + col];
        else if (col < 8) v = g_qe2[k * 4 + (col - 4)];
        g_qeB[col * 64 + k] = f2bf(v);
    }
}

// ---------------- CSR build ----------------
__global__ void k_deg(const int* __restrict__ dstp) {
    int e = blockIdx.x * blockDim.x + threadIdx.x;
    if (e < NE) atomicAdd(&g_deg[dstp[e]], 1);
}
__global__ void k_start() {
    int n = blockIdx.x * blockDim.x + threadIdx.x;
    if (n < NN) {
        int d = g_deg[n];
        int s = atomicAdd(&g_counter, d);
        g_start[n] = s; g_cur[n] = s;
    }
}
__global__ void k_scatter(const int* __restrict__ srcp, const int* __restrict__ dstp) {
    int e = blockIdx.x * blockDim.x + threadIdx.x;
    if (e < NE) {
        int slot = atomicAdd(&g_cur[dstp[e]], 1);
        g_slot[e] = slot;
        g_srccsr[slot] = srcp[e];
    }
}

// ---------------- A-matrix builders (K-augmented bf16 rows) ----------------
// A1 row: [x(32) | onehot(nt) 3 | 1 | 0-pad] -> K=64.  Also writes xi1 = x+ne1.
__device__ __forceinline__ u16 a1val(const void* x, int n, int k, int nt, int isbf) {
    if (k < 32) return f2bf(ldf(x, (size_t)n * 32 + k, isbf));
    if (k == 32 + nt || k == 35) return 0x3F80u;  // bf16 1.0
    return 0;
}
__global__ __launch_bounds__(256) void k_buildA1(const void* x, const int* __restrict__ ntype,
                                                 const void* ne1) {
    int isbf = g_flag;
    int i = blockIdx.x * 256 + threadIdx.x;      // u32 (2 bf16) index
    if (i >= MPAD * 32) return;
    int n = i >> 5, k2 = (i & 31) << 1;
    u32 pk = 0;
    if (n < NN) {
        int nt = ntype[n];
        pk = (u32)a1val(x, n, k2, nt, isbf) | ((u32)a1val(x, n, k2 + 1, nt, isbf) << 16);
        if (k2 < 32) {
            float x0 = ldf(x, (size_t)n * 32 + k2, isbf) + ldf(ne1, nt * 32 + k2, isbf);
            float x1 = ldf(x, (size_t)n * 32 + k2 + 1, isbf) + ldf(ne1, nt * 32 + k2 + 1, isbf);
            ((u32*)g_xi1)[(size_t)n * 16 + (k2 >> 1)] =
                (u32)f2bf(x0) | ((u32)f2bf(x1) << 16);
        }
    }
    ((u32*)g_A1)[i] = pk;
}
// xi2 = bn(xbuf) + ne2[nt]; also fills A2 onehot tail and clears mkey for L2.
__global__ __launch_bounds__(256) void k_xi2(const int* __restrict__ ntype, const void* ne2) {
    int isbf = g_flag;
    int i = blockIdx.x * 256 + threadIdx.x;      // pair index, NN*64 total
    if (i < NN * 4) g_mkey[i] = 0u;
    if (i < NN * 16) {
        int n = i >> 4, q = i & 15;
        int k2 = 128 + q * 2;
        int nt = ntype[n];
        u16 lo = (k2 == 128 + nt || k2 == 131) ? 0x3F80u : 0;
        u16 hi = (k2 + 1 == 128 + nt || k2 + 1 == 131) ? 0x3F80u : 0;
        ((u32*)g_A2)[(size_t)n * 80 + 64 + q] = (u32)lo | ((u32)hi << 16);
    }
    if (i >= NN * 64) return;
    int n = i >> 6, jp = (i & 63) << 1;
    int nt = ntype[n];
    float v0 = g_xbuf[(size_t)n * 128 + jp] * g_bnscale[jp] + g_bnshift[jp]
             + ldf(ne2, nt * 128 + jp, isbf);
    float v1 = g_xbuf[(size_t)n * 128 + jp + 1] * g_bnscale[jp + 1] + g_bnshift[jp + 1]
             + ldf(ne2, nt * 128 + jp + 1, isbf);
    ((u32*)g_xi2)[i] = (u32)f2bf(v0) | ((u32)f2bf(v1) << 16);
}

// ---------------- B-matrix builders (K-major bf16, Bt[col][k]) ----------------
// blocks [0,192): L1a cols (resid/s/d). blocks [192,320): B1bt (block-diag W1).
__global__ void k_buildB1all(const void* ne1, const void* w1,
                             const void* wres1, const void* b1) {
    int isbf = g_flag;
    int bj = blockIdx.x;
    int k = threadIdx.x;         // 128
    if (bj < 192) {
        if (k >= 64) return;
        int j = bj;
        float v = 0.f;
        if (j < 128) {
            if (k < 32) v = ldf(wres1, k * 128 + j, isbf);
            else if (k == 35) v = ldf(b1, j, isbf);
        } else if (j < 136) {
            int h = (j - 128) & 3;
            const float* p = (j < 132) ? g_ps1 : g_pd1;
            if (k < 32) v = p[h * 32 + k];
            else if (k < 35) {
                int tt = k - 32; float a = 0.f;
                for (int c = 0; c < 32; c++)
                    a += ldf(ne1, tt * 32 + c, isbf) * p[h * 32 + c];
                v = a;
            }
        }
        g_B1t[j * 64 + k] = f2bf(v);
    } else {
        int j = bj - 192;        // 0..127
        float v = ((k >> 5) == (j >> 5)) ? ldf(w1, (k & 31) * 128 + j, isbf) : 0.f;
        g_B1bt[j * 128 + k] = f2bf(v);
    }
}
// blocks [0,192): L2a cols. blocks [192,320): B2bt (stacked W2, 0.25 folded).
__global__ void k_buildB2all(const void* ne2, const void* w2,
                             const void* wres2, const void* b2) {
    int isbf = g_flag;
    int bj = blockIdx.x;
    int k = threadIdx.x;         // 256
    if (bj < 192) {
        if (k >= 160) return;
        int j = bj;
        float v = 0.f;
        if (j < 128) {
            if (k < 128) v = g_bnscale[k] * ldf(wres2, k * 128 + j, isbf);
            else if (k == 131) {
                float a = ldf(b2, j, isbf);
                for (int c = 0; c < 128; c++)
                    a += g_bnshift[c] * ldf(wres2, c * 128 + j, isbf);
                v = a;
            }
        } else if (j < 136) {
            int h = (j - 128) & 3;
            const float* p = (j < 132) ? g_ps2 : g_pd2;
            if (k < 128) v = g_bnscale[k] * p[h * 128 + k];
            else if (k < 131) {
                int tt = k - 128; float a = 0.f;
                for (int c = 0; c < 128; c++)
                    a += (g_bnshift[c] + ldf(ne2, tt * 128 + c, isbf)) * p[h * 128 + c];
                v = a;
            }
        }
        g_B2t[j * 160 + k] = f2bf(v);
    } else {
        int j = bj - 192;
        for (int kk = k; kk < 512; kk += 256) {
            float v = 0.25f * ldf(w2, (size_t)(kk & 127) * 512 + (kk >> 7) * 128 + j, isbf);
            g_B2bt[j * 512 + kk] = f2bf(v);
        }
    }
}

// ---------------- generic MFMA GEMM, K-tiled ----------------
// C[64 x 64] per block; 4 waves, each a 16-row strip x 4 col-tiles.
// LAYER: 1=L1a(resid+s/d), 2=L2a(resid+s/d), 3=L1b(+=xbuf, writes A2),
//        4=L2b(+=acc2 resid, writes final output)
template<int K, int KT, int LAYER>
__global__ __launch_bounds__(256) void k_gemm(void* outp) {
    constexpr int KP = KT + 8;
    __shared__ __attribute__((aligned(16))) u16 As[64 * KP];
    __shared__ __attribute__((aligned(16))) u16 Bs[64 * KP];
    const u16* __restrict__ A  = (LAYER == 1) ? g_A1 : (LAYER == 2) ? g_A2
                               : (LAYER == 3) ? g_agg1 : g_agg2;
    const u16* __restrict__ Bt = (LAYER == 1) ? g_B1t : (LAYER == 2) ? g_B2t
                               : (LAYER == 3) ? g_B1bt : g_B2bt;
    int isbf = g_flag;
    const int t = threadIdx.x;
    const int mb = blockIdx.x, cb = blockIdx.y;
    const int wave = t >> 6, lane = t & 63;
    const int lr = lane & 15, lg = lane >> 4;
    f32x4 acc[4] = {};
    constexpr int CH = KT / 8;                 // 16B chunks per row
#pragma unroll 1
    for (int kt = 0; kt < K / KT; kt++) {
        __syncthreads();
        for (int c = t; c < 64 * CH; c += 256) {
            int r = c / CH, o = (c - r * CH) * 8;
            *(s16x8*)&As[r * KP + o] =
                *(const s16x8*)&A[((size_t)(mb * 64 + r)) * K + kt * KT + o];
            *(s16x8*)&Bs[r * KP + o] =
                *(const s16x8*)&Bt[((size_t)(cb * 64 + r)) * K + kt * KT + o];
        }
        __syncthreads();
        const u16* ap  = &As[(wave * 16 + lr) * KP + lg * 8];
        const u16* bp0 = &Bs[lr * KP + lg * 8];
#pragma unroll
        for (int ks = 0; ks < KT / 32; ks++) {
            s16x8 af = *(const s16x8*)(ap + ks * 32);
#pragma unroll
            for (int ct = 0; ct < 4; ct++) {
                s16x8 bf = *(const s16x8*)(bp0 + ct * 16 * KP + ks * 32);
                acc[ct] = __builtin_amdgcn_mfma_f32_16x16x32_bf16(af, bf, acc[ct], 0, 0, 0);
            }
        }
    }
    const int rowb = mb * 64 + wave * 16 + lg * 4;
#pragma unroll
    for (int ct = 0; ct < 4; ct++) {
        int j = cb * 64 + ct * 16 + lr;
#pragma unroll
        for (int r = 0; r < 4; r++) {
            int n = rowb + r;
            if (n >= NN) continue;
            float v = acc[ct][r];
            if (LAYER == 1) {
                if (j < 128)      g_xbuf[(size_t)n * 128 + j] = clampf(v);
                else if (j < 132) g_sbuf[n * 4 + (j - 128)] = clampf(v);
                else if (j < 136) g_dbuf[n * 4 + (j - 132)] = clampf(v);
            } else if (LAYER == 2) {
                if (j < 128)      g_acc2[(size_t)n * 128 + j] = clampf(v);
                else if (j < 132) g_sbuf[n * 4 + (j - 128)] = clampf(v);
                else if (j < 136) g_dbuf[n * 4 + (j - 132)] = clampf(v);
            } else if (LAYER == 3) {
                float* p = &g_xbuf[(size_t)n * 128 + j];
                float x = clampf(*p + v);
                *p = x;
                g_A2[(size_t)n * 160 + j] = f2bf(x);   // A2 data cols
            } else {
                float v2 = clampf(g_acc2[(size_t)n * 128 + j] + v);
                if (isbf) ((u16*)outp)[(size_t)n * 128 + j] = f2bf(v2);
                else      ((float*)outp)[(size_t)n * 128 + j] = v2;
            }
        }
    }
}

// ---------------- MFMA edge logits: PURE STREAM (no gathers) --------------
// A = eattr rows (16 edges x K=64), B = g_qeB (cols 0..3 qe1, 4..7 qe2).
// Writes raw el1+eq1 -> g_alpha, el2+eq2 -> g_el2 as full float4 per edge
// (in-wave transpose via shfl; lane lr==0 writes L1, lane lr==4 writes L2).
__global__ __launch_bounds__(256) void k_edgemm(
    const int* __restrict__ etype, const void* eattr) {
    int isbf = g_flag;
    int t = threadIdx.x, wave = t >> 6, lane = t & 63;
    int lr = lane & 15, lg = lane >> 4;
    s16x8 bf0 = *(const s16x8*)&g_qeB[lr * 64 + lg * 8];
    s16x8 bf1 = *(const s16x8*)&g_qeB[lr * 64 + 32 + lg * 8];
    int ebase = blockIdx.x * 256 + wave * 64;
#pragma unroll 1
    for (int tile = 0; tile < 4; tile++) {
        int e0 = ebase + tile * 16;
        int ea = e0 + lr; if (ea >= NE) ea = NE - 1;   // clamped A-row load
        f32x4 acc = {};
        if (isbf) {
            const u16* ep = (const u16*)eattr + (size_t)ea * 64 + lg * 8;
            s16x8 va = *(const s16x8*)(ep);
            s16x8 vb = *(const s16x8*)(ep + 32);
            acc = __builtin_amdgcn_mfma_f32_16x16x32_bf16(va, bf0, acc, 0, 0, 0);
            acc = __builtin_amdgcn_mfma_f32_16x16x32_bf16(vb, bf1, acc, 0, 0, 0);
        } else {
            const float* ep = (const float*)eattr + (size_t)ea * 64 + lg * 8;
            float4 fa = *(const float4*)(ep);
            float4 fb = *(const float4*)(ep + 4);
            float4 fc = *(const float4*)(ep + 32);
            float4 fd = *(const float4*)(ep + 36);
            s16x8 va, vb;
            va[0] = (short)f2bf(fa.x); va[1] = (short)f2bf(fa.y);
            va[2] = (short)f2bf(fa.z); va[3] = (short)f2bf(fa.w);
            va[4] = (short)f2bf(fb.x); va[5] = (short)f2bf(fb.y);
            va[6] = (short)f2bf(fb.z); va[7] = (short)f2bf(fb.w);
            vb[0] = (short)f2bf(fc.x); vb[1] = (short)f2bf(fc.y);
            vb[2] = (short)f2bf(fc.z); vb[3] = (short)f2bf(fc.w);
            vb[4] = (short)f2bf(fd.x); vb[5] = (short)f2bf(fd.y);
            vb[6] = (short)f2bf(fd.z); vb[7] = (short)f2bf(fd.w);
            acc = __builtin_amdgcn_mfma_f32_16x16x32_bf16(va, bf0, acc, 0, 0, 0);
            acc = __builtin_amdgcn_mfma_f32_16x16x32_bf16(vb, bf1, acc, 0, 0, 0);
        }
#pragma unroll
        for (int r = 0; r < 4; r++) {
            int ee = e0 + lg * 4 + r;
            int lb = lg * 16;
            float v0 = __shfl(acc[r], lb + 0), v1 = __shfl(acc[r], lb + 1);
            float v2 = __shfl(acc[r], lb + 2), v3 = __shfl(acc[r], lb + 3);
            float w0 = __shfl(acc[r], lb + 4), w1 = __shfl(acc[r], lb + 5);
            float w2 = __shfl(acc[r], lb + 6), w3 = __shfl(acc[r], lb + 7);
            if (ee < NE && (lr == 0 || lr == 4)) {
                int et = etype[ee];
                if (lr == 0) {
                    const float* q = g_eq1 + et * 4;
                    *(float4*)(g_alpha + 4 * (size_t)ee) = make_float4(
                        v0 + q[0], v1 + q[1], v2 + q[2], v3 + q[3]);
                } else {
                    const float* q = g_eq2 + et * 4;
                    *(float4*)(g_el2 + 4 * (size_t)ee) = make_float4(
                        w0 + q[0], w1 + q[1], w2 + q[2], w3 + q[3]);
                }
            }
        }
    }
}

// ---------------- edge finalize: alpha = leaky(s+d+el) -> CSR + atomicMax --
__global__ __launch_bounds__(256) void k_edgeadd(
    const int* __restrict__ srcp, const int* __restrict__ dstp, int lyr) {
    int e = blockIdx.x * 256 + threadIdx.x;
    if (e >= NE) return;
    const float* el = (lyr == 1) ? g_alpha : g_el2;
    float4 p = *(const float4*)(el + 4 * (size_t)e);
    int ss = srcp[e], dd = dstp[e];
    float4 sb = *(const float4*)(g_sbuf + ss * 4);
    float4 db = *(const float4*)(g_dbuf + dd * 4);
    float a0 = sb.x + db.x + p.x;
    float a1 = sb.y + db.y + p.y;
    float a2 = sb.z + db.z + p.z;
    float a3 = sb.w + db.w + p.w;
    a0 = clampf(a0 > 0.f ? a0 : 0.2f * a0);
    a1 = clampf(a1 > 0.f ? a1 : 0.2f * a1);
    a2 = clampf(a2 > 0.f ? a2 : 0.2f * a2);
    a3 = clampf(a3 > 0.f ? a3 : 0.2f * a3);
    int slot = g_slot[e];
    *(float4*)(g_acsr + 4 * (size_t)slot) = make_float4(a0, a1, a2, a3);
    u32* mk = &g_mkey[dd * 4];
    atomicMax(&mk[0], menc(a0));
    atomicMax(&mk[1], menc(a1));
    atomicMax(&mk[2], menc(a2));
    atomicMax(&mk[3], menc(a3));
}

// ---------------- fused softmax + aggregation, layer 1 (32-wide xi1) ------
// agg1[n, h*32+k] = (sum_e exp(a_eh - m_h) * xi1[src_e, k]) / z_h
__global__ __launch_bounds__(256) void k_att1() {
    int lane = threadIdx.x & 63;
    int n = blockIdx.x * 4 + (threadIdx.x >> 6);
    if (n >= NN) return;
    int st = g_start[n], dg = g_deg[n];
    uint4 mk = *(const uint4*)&g_mkey[n * 4];
    float m0 = mdec(mk.x), m1 = mdec(mk.y), m2 = mdec(mk.z), m3 = mdec(mk.w);
    int j0 = 2 * lane;
    int hd = j0 >> 5;
    float z0 = 0.f, z1 = 0.f, z2 = 0.f, z3 = 0.f;
    float acc0 = 0.f, acc1 = 0.f;
    for (int base = 0; base < dg; base += 64) {
        int i = base + lane;
        int sidx = 0; float c0 = 0.f, c1 = 0.f, c2 = 0.f, c3 = 0.f;
        if (i < dg) {
            float4 a = *(const float4*)(g_acsr + 4 * (size_t)(st + i));
            sidx = g_srccsr[st + i];
            c0 = expf(a.x - m0); c1 = expf(a.y - m1);
            c2 = expf(a.z - m2); c3 = expf(a.w - m3);
            z0 += c0; z1 += c1; z2 += c2; z3 += c3;
        }
        int cnt = min(64, dg - base);
        for (int jj = 0; jj < cnt; jj++) {
            int s2 = __shfl(sidx, jj);
            float b0 = __shfl(c0, jj), b1 = __shfl(c1, jj);
            float b2v = __shfl(c2, jj), b3 = __shfl(c3, jj);
            float cs = hd == 0 ? b0 : hd == 1 ? b1 : hd == 2 ? b2v : b3;
            u32 hv = *(const u32*)(g_xi1 + (size_t)s2 * 32 + (j0 & 31));
            acc0 += bf2f((u16)(hv & 0xffff)) * cs;
            acc1 += bf2f((u16)(hv >> 16)) * cs;
        }
    }
    for (int mk2 = 32; mk2 >= 1; mk2 >>= 1) {
        z0 += __shfl_xor(z0, mk2); z1 += __shfl_xor(z1, mk2);
        z2 += __shfl_xor(z2, mk2); z3 += __shfl_xor(z3, mk2);
    }
    float iv = 1.f / ((hd == 0 ? z0 : hd == 1 ? z1 : hd == 2 ? z2 : z3) + 1e-16f);
    ((u32*)g_agg1)[((size_t)n * 128 + j0) >> 1] =
        (u32)f2bf(acc0 * iv) | ((u32)f2bf(acc1 * iv) << 16);
}

// ---------------- batch norm ----------------
__global__ __launch_bounds__(256) void k_bnstats() {
    int t = threadIdx.x;
    int j = t & 127;
    int r0 = blockIdx.x * 2 + (t >> 7);
    float s = 0.f, ss = 0.f;
    for (int r = r0; r < NN; r += 500) {
        float v = g_xbuf[(size_t)r * 128 + j];
        s += v; ss += v * v;
    }
    atomicAdd(&g_bnsum[j], s);
    atomicAdd(&g_bnsumsq[j], ss);
}
__global__ void k_bnfin(const void* gamma, const void* beta) {
    int isbf = g_flag;
    int j = threadIdx.x;  // 128
    float mu = g_bnsum[j] * (1.f / NN);
    float var = fmaxf(g_bnsumsq[j] * (1.f / NN) - mu * mu, 0.f);
    float rstd = rsqrtf(var + 1e-5f);
    float sc = ldf(gamma, j, isbf) * rstd;
    g_bnscale[j] = sc;
    g_bnshift[j] = ldf(beta, j, isbf) - mu * sc;
}

// ---------------- fused softmax + aggregation, layer 2 (128-wide xi2) -----
// agg2[n, h*128+c] = (sum_e exp(a_eh - m_h) * xi2[src_e, c]) / z_h
__global__ __launch_bounds__(256) void k_att2() {
    int lane = threadIdx.x & 63;
    int n = blockIdx.x * 4 + (threadIdx.x >> 6);
    if (n >= NN) return;
    int st = g_start[n], dg = g_deg[n];
    uint4 mk = *(const uint4*)&g_mkey[n * 4];
    float m0 = mdec(mk.x), m1 = mdec(mk.y), m2 = mdec(mk.z), m3 = mdec(mk.w);
    int c0 = 2 * lane;
    float z0 = 0.f, z1 = 0.f, z2 = 0.f, z3 = 0.f;
    float a00 = 0.f, a01 = 0.f, a10 = 0.f, a11 = 0.f;
    float a20 = 0.f, a21 = 0.f, a30 = 0.f, a31 = 0.f;
    for (int base = 0; base < dg; base += 64) {
        int i = base + lane;
        int sidx = 0; float c0f = 0.f, c1f = 0.f, c2f = 0.f, c3f = 0.f;
        if (i < dg) {
            float4 a = *(const float4*)(g_acsr + 4 * (size_t)(st + i));
            sidx = g_srccsr[st + i];
            c0f = expf(a.x - m0); c1f = expf(a.y - m1);
            c2f = expf(a.z - m2); c3f = expf(a.w - m3);
            z0 += c0f; z1 += c1f; z2 += c2f; z3 += c3f;
        }
        int cnt = min(64, dg - base);
        for (int jj = 0; jj < cnt; jj++) {
            int s2 = __shfl(sidx, jj);
            float b0 = __shfl(c0f, jj), b1 = __shfl(c1f, jj);
            float b2v = __shfl(c2f, jj), b3 = __shfl(c3f, jj);
            u32 hv = *(const u32*)(g_xi2 + (size_t)s2 * 128 + c0);
            float lo = bf2f((u16)(hv & 0xffff)), hi = bf2f((u16)(hv >> 16));
            a00 += lo * b0;  a01 += hi * b0;
            a10 += lo * b1;  a11 += hi * b1;
            a20 += lo * b2v; a21 += hi * b2v;
            a30 += lo * b3;  a31 += hi * b3;
        }
    }
    for (int mk2 = 32; mk2 >= 1; mk2 >>= 1) {
        z0 += __shfl_xor(z0, mk2); z1 += __shfl_xor(z1, mk2);
        z2 += __shfl_xor(z2, mk2); z3 += __shfl_xor(z3, mk2);
    }
    float iv0 = 1.f / (z0 + 1e-16f), iv1 = 1.f / (z1 + 1e-16f);
    float iv2 = 1.f / (z2 + 1e-16f), iv3 = 1.f / (z3 + 1e-16f);
    u32* out = (u32*)g_agg2 + (((size_t)n * 512 + c0) >> 1);
    out[0]   = (u32)f2bf(a00 * iv0) | ((u32)f2bf(a01 * iv0) << 16);
    out[64]  = (u32)f2bf(a10 * iv1) | ((u32)f2bf(a11 * iv1) << 16);
    out[128] = (u32)f2bf(a20 * iv2) | ((u32)f2bf(a21 * iv2) << 16);
    out[192] = (u32)f2bf(a30 * iv3) | ((u32)f2bf(a31 * iv3) << 16);
}

// ---------------- launcher ----------------
extern "C" void kernel_launch(void* const* d_in, const int* in_sizes, int n_in,
                              void* d_out, int out_size, void* d_ws, size_t ws_size,
                              hipStream_t stream) {
    const void* x     = d_in[0];
    const int* ei     = (const int*)d_in[1];
    const int* ntype  = (const int*)d_in[2];
    const void* eattr = d_in[3];
    const int* etype  = (const int*)d_in[4];
    const void* ne1   = d_in[5];
    const void* w1    = d_in[6];
    const void* we1   = d_in[7];
    const void* asrc1 = d_in[8];
    const void* adst1 = d_in[9];
    const void* aedge1= d_in[10];
    const void* ee1   = d_in[11];
    const void* wres1 = d_in[12];
    const void* b1    = d_in[13];
    const void* gamma = d_in[14];
    const void* beta  = d_in[15];
    const void* ne2   = d_in[16];
    const void* w2    = d_in[17];
    const void* we2   = d_in[18];
    const void* asrc2 = d_in[19];
    const void* adst2 = d_in[20];
    const void* aedge2= d_in[21];
    const void* ee2   = d_in[22];
    const void* wres2 = d_in[23];
    const void* b2    = d_in[24];
    (void)in_sizes; (void)n_in; (void)out_size; (void)d_ws; (void)ws_size;

    const int* srcp = ei;
    const int* dstp = ei + NE;

    k_zero<<<(NN * 4 + 255) / 256, 256, 0, stream>>>((const u16*)x);
    k_prep<<<112, 256, 0, stream>>>(we1, aedge1, we2, aedge2,
                                    w1, asrc1, adst1, w2, asrc2, adst2);
    k_prep2<<<2, 256, 0, stream>>>(ee1, ee2);
    k_deg<<<1563, 256, 0, stream>>>(dstp);
    k_start<<<196, 256, 0, stream>>>();
    k_scatter<<<1563, 256, 0, stream>>>(srcp, dstp);

    // ---- edge logits (pure stream over eattr, both layers) ----
    k_edgemm<<<(NE + 255) / 256, 256, 0, stream>>>(etype, eattr);

    // ---- layer 1 ----
    k_buildA1<<<(MPAD * 32 + 255) / 256, 256, 0, stream>>>(x, ntype, ne1);
    k_buildB1all<<<320, 128, 0, stream>>>(ne1, w1, wres1, b1);
    k_gemm<64, 64, 1><<<dim3(MPAD / 64, 3), 256, 0, stream>>>(nullptr);
    k_edgeadd<<<1563, 256, 0, stream>>>(srcp, dstp, 1);
    k_att1<<<12500, 256, 0, stream>>>();
    k_gemm<128, 128, 3><<<dim3(MPAD / 64, 2), 256, 0, stream>>>(nullptr);

    // ---- batch norm ----
    k_bnstats<<<250, 256, 0, stream>>>();
    k_bnfin<<<1, 128, 0, stream>>>(gamma, beta);

    // ---- layer 2 ----
    k_xi2<<<12500, 256, 0, stream>>>(ntype, ne2);   // + A2 tail + mkey clear
    k_buildB2all<<<320, 256, 0, stream>>>(ne2, w2, wres2, b2);
    k_gemm<160, 160, 2><<<dim3(MPAD / 64, 3), 256, 0, stream>>>(nullptr);
    k_edgeadd<<<1563, 256, 0, stream>>>(srcp, dstp, 2);
    k_att2<<<12500, 256, 0, stream>>>();
    k_gemm<512, 128, 4><<<dim3(MPAD / 64, 2), 256, 0, stream>>>(d_out);
}

// Round 10
// 582.086 us; speedup vs baseline: 1.1892x; 1.1892x over previous
//
#include <hip/hip_runtime.h>
#include <hip/hip_bf16.h>

typedef unsigned short u16;
typedef unsigned int u32;

constexpr int NN = 50000;   // nodes
constexpr int NE = 400000;  // edges
constexpr int MPAD = 50048; // 782 * 64 row-padded M

typedef __attribute__((ext_vector_type(8))) short s16x8;
typedef __attribute__((ext_vector_type(4))) float f32x4;

__device__ __forceinline__ float bf2f(u16 u) {
    union { u32 i; float f; } v; v.i = ((u32)u) << 16; return v.f;
}
__device__ __forceinline__ u16 f2bf(float f) {
    union { float f; u32 i; } v; v.f = f;
    u32 r = v.i + 0x7fffu + ((v.i >> 16) & 1u);
    return (u16)(r >> 16);
}
// dtype-adaptive float load: isbf=1 -> bf16 storage, isbf=0 -> f32 storage
__device__ __forceinline__ float ldf(const void* p, size_t i, int isbf) {
    if (isbf) return bf2f(((const u16*)p)[i]);
    return ((const float*)p)[i];
}
__device__ __forceinline__ float clampf(float v) {
    // kills inf AND NaN (fmaxf(NaN,x)=x on HIP); never binds for sane values
    return fminf(fmaxf(v, -1e4f), 1e4f);
}

// ---------------- static device scratch (independent of d_ws) ----------------
__device__ int   g_flag;
__device__ int   g_counter;
__device__ float g_qe1[256], g_qe2[256];
__device__ float g_eq1[16], g_eq2[16];
__device__ float g_ps1[128], g_pd1[128], g_ps2[512], g_pd2[512];
__device__ float g_bnsum[128], g_bnsumsq[128], g_bnscale[128], g_bnshift[128];
__device__ int   g_deg[NN], g_start[NN], g_cur[NN];
__device__ int   g_eidx[NE];
__device__ __attribute__((aligned(16))) float g_sbuf[NN * 4];
__device__ __attribute__((aligned(16))) float g_dbuf[NN * 4];
__device__ __attribute__((aligned(16))) float g_alpha[(size_t)NE * 4];  // el1 -> alpha
__device__ __attribute__((aligned(16))) float g_el2[(size_t)NE * 4];    // raw el2
__device__ __attribute__((aligned(16))) float g_xbuf[(size_t)NN * 128];
__device__ __attribute__((aligned(16))) float g_acc2[(size_t)NN * 128];
// MFMA GEMM operands (bf16). A rows padded to MPAD; B stored K-major (Bt[j][k]).
__device__ __attribute__((aligned(16))) u16 g_A1[(size_t)MPAD * 64];
__device__ __attribute__((aligned(16))) u16 g_A2[(size_t)MPAD * 160];
__device__ __attribute__((aligned(16))) u16 g_B1t[192 * 64];
__device__ __attribute__((aligned(16))) u16 g_B1bt[128 * 128];
__device__ __attribute__((aligned(16))) u16 g_B2t[192 * 160];
__device__ __attribute__((aligned(16))) u16 g_B2bt[128 * 512];
// qe packed as B-matrix for edge MFMA: qeB[col][k], col 0..3=qe1 h, 4..7=qe2 h
__device__ __attribute__((aligned(16))) u16 g_qeB[16 * 64];
// per-node attention-input tables (bf16) + aggregated messages (bf16)
__device__ __attribute__((aligned(16))) u16 g_xi1[(size_t)NN * 32];
__device__ __attribute__((aligned(16))) u16 g_xi2[(size_t)NN * 128];
__device__ __attribute__((aligned(16))) u16 g_agg1[(size_t)MPAD * 128];
__device__ __attribute__((aligned(16))) u16 g_agg2[(size_t)MPAD * 512];

// ---------------- init (+ dtype detect folded in) ----------------
__global__ void k_zero(const u16* x) {
    int i = blockIdx.x * blockDim.x + threadIdx.x;
    if (i < NN) g_deg[i] = 0;
    if (i < 128) { g_bnsum[i] = 0.f; g_bnsumsq[i] = 0.f; }
    if (i == 0) {
        int cnt = 0;
        for (int j = 0; j < 64; j++) {
            u16 u = x[2 * j];
            int ex = (u >> 7) & 0xff;
            if (ex >= 100 && ex <= 140) cnt++;
        }
        g_flag = (cnt >= 40) ? 1 : 0;
        g_counter = 0;
    }
}

// Folded projections, wave-cooperative: 16 lanes per output, 1792 outputs.
__global__ __launch_bounds__(256) void k_prep(
    const void* we1, const void* ae1, const void* we2, const void* ae2,
    const void* w1, const void* as1, const void* ad1,
    const void* w2, const void* as2, const void* ad2) {
    int isbf = g_flag;
    int t = threadIdx.x;
    int idx = blockIdx.x * 16 + (t >> 4);   // 112 blocks x 16 groups = 1792
    int s = t & 15;
    float a = 0.f;
    if (idx < 256) {                         // qe1
        int k = idx >> 2, hd = idx & 3;
        for (int c = s; c < 32; c += 16)
            a += ldf(we1, k * 128 + hd * 32 + c, isbf) * ldf(ae1, hd * 32 + c, isbf);
    } else if (idx < 512) {                  // qe2
        int i2 = idx - 256;
        int k = i2 >> 2, hd = i2 & 3;
        for (int c = s; c < 128; c += 16)
            a += ldf(we2, k * 512 + hd * 128 + c, isbf) * ldf(ae2, hd * 128 + c, isbf);
    } else if (idx < 768) {                  // ps1 / pd1
        int i2 = idx - 512;
        int isd = i2 >> 7, j = i2 & 127;
        int h = j >> 5, k = j & 31;
        const void* av = isd ? ad1 : as1;
        for (int c = s; c < 32; c += 16)
            a += ldf(w1, k * 128 + h * 32 + c, isbf) * ldf(av, h * 32 + c, isbf);
    } else {                                 // ps2 / pd2
        int i2 = idx - 768;
        int isd = i2 >> 9, j = i2 & 511;
        int h = j >> 7, k = j & 127;
        const void* av = isd ? ad2 : as2;
        for (int c = s; c < 128; c += 16)
            a += ldf(w2, (size_t)k * 512 + h * 128 + c, isbf) * ldf(av, h * 128 + c, isbf);
    }
#pragma unroll
    for (int mk = 8; mk >= 1; mk >>= 1) a += __shfl_xor(a, mk);
    if (s == 0) {
        if (idx < 256) g_qe1[idx] = a;
        else if (idx < 512) g_qe2[idx - 256] = a;
        else if (idx < 768) {
            int i2 = idx - 512;
            if (i2 >> 7) g_pd1[i2 & 127] = a; else g_ps1[i2 & 127] = a;
        } else {
            int i2 = idx - 768;
            if (i2 >> 9) g_pd2[i2 & 511] = a; else g_ps2[i2 & 511] = a;
        }
    }
}
// eq_l[et][h] = sum_k ee_l[et,k] * qe_l[k,h]; also packs g_qeB[col][k].
__global__ void k_prep2(const void* ee1, const void* ee2) {
    int isbf = g_flag;
    int t = threadIdx.x;
    int idx = blockIdx.x * 16 + (t >> 4);    // 2 blocks x 16 = 32
    int s = t & 15;
    int lyr = idx >> 4;
    int et = (idx >> 2) & 3, h = idx & 3;
    const void* ee = lyr ? ee2 : ee1;
    const float* qe = lyr ? g_qe2 : g_qe1;
    float a = 0.f;
    for (int k = s; k < 64; k += 16)
        a += ldf(ee, et * 64 + k, isbf) * qe[k * 4 + h];
#pragma unroll
    for (int mk = 8; mk >= 1; mk >>= 1) a += __shfl_xor(a, mk);
    if (s == 0) {
        if (lyr) g_eq2[et * 4 + h] = a; else g_eq1[et * 4 + h] = a;
    }
    // pack qeB: 1024 entries, 512 threads across 2 blocks -> 2 each
    int base = blockIdx.x * 256 + t;
    for (int i = base; i < 1024; i += 512) {
        int col = i >> 6, k = i & 63;
        float v = 0.f;
        if (col < 4) v = g_qe1[k * 4 + col];
        else if (col < 8) v = g_qe2[k * 4 + (col - 4)];
        g_qeB[col * 64 + k] = f2bf(v);
    }
}

// ---------------- CSR build ----------------
__global__ void k_deg(const int* __restrict__ dstp) {
    int e = blockIdx.x * blockDim.x + threadIdx.x;
    if (e < NE) atomicAdd(&g_deg[dstp[e]], 1);
}
__global__ void k_start() {
    int n = blockIdx.x * blockDim.x + threadIdx.x;
    if (n < NN) {
        int d = g_deg[n];
        int s = atomicAdd(&g_counter, d);
        g_start[n] = s; g_cur[n] = s;
    }
}
__global__ void k_scatter(const int* __restrict__ dstp) {
    int e = blockIdx.x * blockDim.x + threadIdx.x;
    if (e < NE) {
        int slot = atomicAdd(&g_cur[dstp[e]], 1);
        g_eidx[slot] = e;
    }
}

// ---------------- A-matrix builders (K-augmented bf16 rows) ----------------
// A1 row: [x(32) | onehot(nt) 3 | 1 | 0-pad] -> K=64.  Also writes xi1 = x+ne1.
__device__ __forceinline__ u16 a1val(const void* x, int n, int k, int nt, int isbf) {
    if (k < 32) return f2bf(ldf(x, (size_t)n * 32 + k, isbf));
    if (k == 32 + nt || k == 35) return 0x3F80u;  // bf16 1.0
    return 0;
}
__global__ __launch_bounds__(256) void k_buildA1(const void* x, const int* __restrict__ ntype,
                                                 const void* ne1) {
    int isbf = g_flag;
    int i = blockIdx.x * 256 + threadIdx.x;      // u32 (2 bf16) index
    if (i >= MPAD * 32) return;
    int n = i >> 5, k2 = (i & 31) << 1;
    u32 pk = 0;
    if (n < NN) {
        int nt = ntype[n];
        pk = (u32)a1val(x, n, k2, nt, isbf) | ((u32)a1val(x, n, k2 + 1, nt, isbf) << 16);
        if (k2 < 32) {
            float x0 = ldf(x, (size_t)n * 32 + k2, isbf) + ldf(ne1, nt * 32 + k2, isbf);
            float x1 = ldf(x, (size_t)n * 32 + k2 + 1, isbf) + ldf(ne1, nt * 32 + k2 + 1, isbf);
            ((u32*)g_xi1)[(size_t)n * 16 + (k2 >> 1)] =
                (u32)f2bf(x0) | ((u32)f2bf(x1) << 16);
        }
    }
    ((u32*)g_A1)[i] = pk;
}
// xi2 = bn(xbuf) + ne2[nt]; also fills A2 onehot tail cols.
__global__ __launch_bounds__(256) void k_xi2(const int* __restrict__ ntype, const void* ne2) {
    int isbf = g_flag;
    int i = blockIdx.x * 256 + threadIdx.x;      // pair index, NN*64 total
    if (i < NN * 16) {
        int n = i >> 4, q = i & 15;
        int k2 = 128 + q * 2;
        int nt = ntype[n];
        u16 lo = (k2 == 128 + nt || k2 == 131) ? 0x3F80u : 0;
        u16 hi = (k2 + 1 == 128 + nt || k2 + 1 == 131) ? 0x3F80u : 0;
        ((u32*)g_A2)[(size_t)n * 80 + 64 + q] = (u32)lo | ((u32)hi << 16);
    }
    if (i >= NN * 64) return;
    int n = i >> 6, jp = (i & 63) << 1;
    int nt = ntype[n];
    float v0 = g_xbuf[(size_t)n * 128 + jp] * g_bnscale[jp] + g_bnshift[jp]
             + ldf(ne2, nt * 128 + jp, isbf);
    float v1 = g_xbuf[(size_t)n * 128 + jp + 1] * g_bnscale[jp + 1] + g_bnshift[jp + 1]
             + ldf(ne2, nt * 128 + jp + 1, isbf);
    ((u32*)g_xi2)[i] = (u32)f2bf(v0) | ((u32)f2bf(v1) << 16);
}

// ---------------- B-matrix builders (K-major bf16, Bt[col][k]) ----------------
// blocks [0,192): L1a cols (resid/s/d). blocks [192,320): B1bt (block-diag W1).
__global__ void k_buildB1all(const void* ne1, const void* w1,
                             const void* wres1, const void* b1) {
    int isbf = g_flag;
    int bj = blockIdx.x;
    int k = threadIdx.x;         // 128
    if (bj < 192) {
        if (k >= 64) return;
        int j = bj;
        float v = 0.f;
        if (j < 128) {
            if (k < 32) v = ldf(wres1, k * 128 + j, isbf);
            else if (k == 35) v = ldf(b1, j, isbf);
        } else if (j < 136) {
            int h = (j - 128) & 3;
            const float* p = (j < 132) ? g_ps1 : g_pd1;
            if (k < 32) v = p[h * 32 + k];
            else if (k < 35) {
                int tt = k - 32; float a = 0.f;
                for (int c = 0; c < 32; c++)
                    a += ldf(ne1, tt * 32 + c, isbf) * p[h * 32 + c];
                v = a;
            }
        }
        g_B1t[j * 64 + k] = f2bf(v);
    } else {
        int j = bj - 192;        // 0..127
        float v = ((k >> 5) == (j >> 5)) ? ldf(w1, (k & 31) * 128 + j, isbf) : 0.f;
        g_B1bt[j * 128 + k] = f2bf(v);
    }
}
// blocks [0,192): L2a cols. blocks [192,320): B2bt (stacked W2, 0.25 folded).
__global__ void k_buildB2all(const void* ne2, const void* w2,
                             const void* wres2, const void* b2) {
    int isbf = g_flag;
    int bj = blockIdx.x;
    int k = threadIdx.x;         // 256
    if (bj < 192) {
        if (k >= 160) return;
        int j = bj;
        float v = 0.f;
        if (j < 128) {
            if (k < 128) v = g_bnscale[k] * ldf(wres2, k * 128 + j, isbf);
            else if (k == 131) {
                float a = ldf(b2, j, isbf);
                for (int c = 0; c < 128; c++)
                    a += g_bnshift[c] * ldf(wres2, c * 128 + j, isbf);
                v = a;
            }
        } else if (j < 136) {
            int h = (j - 128) & 3;
            const float* p = (j < 132) ? g_ps2 : g_pd2;
            if (k < 128) v = g_bnscale[k] * p[h * 128 + k];
            else if (k < 131) {
                int tt = k - 128; float a = 0.f;
                for (int c = 0; c < 128; c++)
                    a += (g_bnshift[c] + ldf(ne2, tt * 128 + c, isbf)) * p[h * 128 + c];
                v = a;
            }
        }
        g_B2t[j * 160 + k] = f2bf(v);
    } else {
        int j = bj - 192;
        for (int kk = k; kk < 512; kk += 256) {
            float v = 0.25f * ldf(w2, (size_t)(kk & 127) * 512 + (kk >> 7) * 128 + j, isbf);
            g_B2bt[j * 512 + kk] = f2bf(v);
        }
    }
}

// ---------------- generic MFMA GEMM, K-tiled ----------------
// C[64 x 64] per block; 4 waves, each a 16-row strip x 4 col-tiles.
// LAYER: 1=L1a(resid+s/d), 2=L2a(resid+s/d), 3=L1b(+=xbuf, writes A2),
//        4=L2b(+=acc2 resid, writes final output)
template<int K, int KT, int LAYER>
__global__ __launch_bounds__(256) void k_gemm(void* outp) {
    constexpr int KP = KT + 8;
    __shared__ __attribute__((aligned(16))) u16 As[64 * KP];
    __shared__ __attribute__((aligned(16))) u16 Bs[64 * KP];
    const u16* __restrict__ A  = (LAYER == 1) ? g_A1 : (LAYER == 2) ? g_A2
                               : (LAYER == 3) ? g_agg1 : g_agg2;
    const u16* __restrict__ Bt = (LAYER == 1) ? g_B1t : (LAYER == 2) ? g_B2t
                               : (LAYER == 3) ? g_B1bt : g_B2bt;
    int isbf = g_flag;
    const int t = threadIdx.x;
    const int mb = blockIdx.x, cb = blockIdx.y;
    const int wave = t >> 6, lane = t & 63;
    const int lr = lane & 15, lg = lane >> 4;
    f32x4 acc[4] = {};
    constexpr int CH = KT / 8;                 // 16B chunks per row
#pragma unroll 1
    for (int kt = 0; kt < K / KT; kt++) {
        __syncthreads();
        for (int c = t; c < 64 * CH; c += 256) {
            int r = c / CH, o = (c - r * CH) * 8;
            *(s16x8*)&As[r * KP + o] =
                *(const s16x8*)&A[((size_t)(mb * 64 + r)) * K + kt * KT + o];
            *(s16x8*)&Bs[r * KP + o] =
                *(const s16x8*)&Bt[((size_t)(cb * 64 + r)) * K + kt * KT + o];
        }
        __syncthreads();
        const u16* ap  = &As[(wave * 16 + lr) * KP + lg * 8];
        const u16* bp0 = &Bs[lr * KP + lg * 8];
#pragma unroll
        for (int ks = 0; ks < KT / 32; ks++) {
            s16x8 af = *(const s16x8*)(ap + ks * 32);
#pragma unroll
            for (int ct = 0; ct < 4; ct++) {
                s16x8 bf = *(const s16x8*)(bp0 + ct * 16 * KP + ks * 32);
                acc[ct] = __builtin_amdgcn_mfma_f32_16x16x32_bf16(af, bf, acc[ct], 0, 0, 0);
            }
        }
    }
    const int rowb = mb * 64 + wave * 16 + lg * 4;
#pragma unroll
    for (int ct = 0; ct < 4; ct++) {
        int j = cb * 64 + ct * 16 + lr;
#pragma unroll
        for (int r = 0; r < 4; r++) {
            int n = rowb + r;
            if (n >= NN) continue;
            float v = acc[ct][r];
            if (LAYER == 1) {
                if (j < 128)      g_xbuf[(size_t)n * 128 + j] = clampf(v);
                else if (j < 132) g_sbuf[n * 4 + (j - 128)] = clampf(v);
                else if (j < 136) g_dbuf[n * 4 + (j - 132)] = clampf(v);
            } else if (LAYER == 2) {
                if (j < 128)      g_acc2[(size_t)n * 128 + j] = clampf(v);
                else if (j < 132) g_sbuf[n * 4 + (j - 128)] = clampf(v);
                else if (j < 136) g_dbuf[n * 4 + (j - 132)] = clampf(v);
            } else if (LAYER == 3) {
                float* p = &g_xbuf[(size_t)n * 128 + j];
                float x = clampf(*p + v);
                *p = x;
                g_A2[(size_t)n * 160 + j] = f2bf(x);   // A2 data cols
            } else {
                float v2 = clampf(g_acc2[(size_t)n * 128 + j] + v);
                if (isbf) ((u16*)outp)[(size_t)n * 128 + j] = f2bf(v2);
                else      ((float*)outp)[(size_t)n * 128 + j] = v2;
            }
        }
    }
}

// ---------------- MFMA edge logits: pure stream, LDS-transposed epilogue ---
// A = eattr rows (16 edges x K=64), B = g_qeB (cols 0..3 qe1, 4..7 qe2).
// Compute loop stages C-fragments to LDS; epilogue: lane i writes full
// float4 for edge ebase+i (layer1 -> g_alpha, layer2 -> g_el2), coalesced.
__global__ __launch_bounds__(256) void k_edgemm(
    const int* __restrict__ etype, const void* eattr) {
    __shared__ float st[4][4][16][8];   // [wave][tile][edge][col] = 8KB
    int isbf = g_flag;
    int t = threadIdx.x, wave = t >> 6, lane = t & 63;
    int lr = lane & 15, lg = lane >> 4;
    s16x8 bf0 = *(const s16x8*)&g_qeB[lr * 64 + lg * 8];
    s16x8 bf1 = *(const s16x8*)&g_qeB[lr * 64 + 32 + lg * 8];
    int ebase = blockIdx.x * 256 + wave * 64;
#pragma unroll 1
    for (int tile = 0; tile < 4; tile++) {
        int e0 = ebase + tile * 16;
        int ea = e0 + lr; if (ea >= NE) ea = NE - 1;   // clamped A-row load
        f32x4 acc = {};
        if (isbf) {
            const u16* ep = (const u16*)eattr + (size_t)ea * 64 + lg * 8;
            s16x8 va = *(const s16x8*)(ep);
            s16x8 vb = *(const s16x8*)(ep + 32);
            acc = __builtin_amdgcn_mfma_f32_16x16x32_bf16(va, bf0, acc, 0, 0, 0);
            acc = __builtin_amdgcn_mfma_f32_16x16x32_bf16(vb, bf1, acc, 0, 0, 0);
        } else {
            const float* ep = (const float*)eattr + (size_t)ea * 64 + lg * 8;
            float4 fa = *(const float4*)(ep);
            float4 fb = *(const float4*)(ep + 4);
            float4 fc = *(const float4*)(ep + 32);
            float4 fd = *(const float4*)(ep + 36);
            s16x8 va, vb;
            va[0] = (short)f2bf(fa.x); va[1] = (short)f2bf(fa.y);
            va[2] = (short)f2bf(fa.z); va[3] = (short)f2bf(fa.w);
            va[4] = (short)f2bf(fb.x); va[5] = (short)f2bf(fb.y);
            va[6] = (short)f2bf(fb.z); va[7] = (short)f2bf(fb.w);
            vb[0] = (short)f2bf(fc.x); vb[1] = (short)f2bf(fc.y);
            vb[2] = (short)f2bf(fc.z); vb[3] = (short)f2bf(fc.w);
            vb[4] = (short)f2bf(fd.x); vb[5] = (short)f2bf(fd.y);
            vb[6] = (short)f2bf(fd.z); vb[7] = (short)f2bf(fd.w);
            acc = __builtin_amdgcn_mfma_f32_16x16x32_bf16(va, bf0, acc, 0, 0, 0);
            acc = __builtin_amdgcn_mfma_f32_16x16x32_bf16(vb, bf1, acc, 0, 0, 0);
        }
        if (lr < 8) {
#pragma unroll
            for (int r = 0; r < 4; r++) st[wave][tile][lg * 4 + r][lr] = acc[r];
        }
    }
    __syncthreads();
    int ee = ebase + lane;
    if (ee < NE) {
        int et = etype[ee];
        const float* s = &st[wave][lane >> 4][lane & 15][0];
        const float* q1 = g_eq1 + et * 4;
        const float* q2 = g_eq2 + et * 4;
        *(float4*)(g_alpha + 4 * (size_t)ee) = make_float4(
            s[0] + q1[0], s[1] + q1[1], s[2] + q1[2], s[3] + q1[3]);
        *(float4*)(g_el2 + 4 * (size_t)ee) = make_float4(
            s[4] + q2[0], s[5] + q2[1], s[6] + q2[2], s[7] + q2[3]);
    }
}

// ---------------- light edge finalize: alpha = leaky(s+d+el) --------------
// lyr==1: el read from g_alpha in-place; lyr==2: el read from g_el2.
__global__ __launch_bounds__(256) void k_edgeadd(
    const int* __restrict__ srcp, const int* __restrict__ dstp, int lyr) {
    int e = blockIdx.x * 256 + threadIdx.x;
    if (e >= NE) return;
    const float* el = (lyr == 1) ? g_alpha : g_el2;
    float4 p = *(const float4*)(el + 4 * (size_t)e);
    int ss = srcp[e], dd = dstp[e];
    float4 sb = *(const float4*)(g_sbuf + ss * 4);
    float4 db = *(const float4*)(g_dbuf + dd * 4);
    float a0 = sb.x + db.x + p.x;
    float a1 = sb.y + db.y + p.y;
    float a2 = sb.z + db.z + p.z;
    float a3 = sb.w + db.w + p.w;
    a0 = a0 > 0.f ? a0 : 0.2f * a0;
    a1 = a1 > 0.f ? a1 : 0.2f * a1;
    a2 = a2 > 0.f ? a2 : 0.2f * a2;
    a3 = a3 > 0.f ? a3 : 0.2f * a3;
    *(float4*)(g_alpha + 4 * (size_t)e) = make_float4(
        clampf(a0), clampf(a1), clampf(a2), clampf(a3));
}

// ---------------- fused softmax + aggregation, layer 1 (32-wide xi1) ------
// agg1[n, h*32+k] = (sum_e exp(a_eh - m_h) * xi1[src_e, k]) / z_h
__global__ __launch_bounds__(256) void k_att1(const int* __restrict__ srcp) {
    int lane = threadIdx.x & 63;
    int n = blockIdx.x * 4 + (threadIdx.x >> 6);
    if (n >= NN) return;
    int st = g_start[n], dg = g_deg[n];
    float m0 = -1e30f, m1 = -1e30f, m2 = -1e30f, m3 = -1e30f;
    for (int i = lane; i < dg; i += 64) {
        int e = g_eidx[st + i];
        float4 a = *(const float4*)(g_alpha + 4 * (size_t)e);
        m0 = fmaxf(m0, a.x); m1 = fmaxf(m1, a.y);
        m2 = fmaxf(m2, a.z); m3 = fmaxf(m3, a.w);
    }
    for (int mk = 32; mk >= 1; mk >>= 1) {
        m0 = fmaxf(m0, __shfl_xor(m0, mk)); m1 = fmaxf(m1, __shfl_xor(m1, mk));
        m2 = fmaxf(m2, __shfl_xor(m2, mk)); m3 = fmaxf(m3, __shfl_xor(m3, mk));
    }
    if (m0 < -1e29f) m0 = 0.f;
    if (m1 < -1e29f) m1 = 0.f;
    if (m2 < -1e29f) m2 = 0.f;
    if (m3 < -1e29f) m3 = 0.f;
    int j0 = 2 * lane;
    int hd = j0 >> 5;
    float z0 = 0.f, z1 = 0.f, z2 = 0.f, z3 = 0.f;
    float acc0 = 0.f, acc1 = 0.f;
    for (int base = 0; base < dg; base += 64) {
        int i = base + lane;
        int sidx = 0; float c0 = 0.f, c1 = 0.f, c2 = 0.f, c3 = 0.f;
        if (i < dg) {
            int e = g_eidx[st + i];
            float4 a = *(const float4*)(g_alpha + 4 * (size_t)e);
            sidx = srcp[e];
            c0 = expf(a.x - m0); c1 = expf(a.y - m1);
            c2 = expf(a.z - m2); c3 = expf(a.w - m3);
            z0 += c0; z1 += c1; z2 += c2; z3 += c3;
        }
        int cnt = min(64, dg - base);
        for (int jj = 0; jj < cnt; jj++) {
            int s2 = __shfl(sidx, jj);
            float b0 = __shfl(c0, jj), b1 = __shfl(c1, jj);
            float b2v = __shfl(c2, jj), b3 = __shfl(c3, jj);
            float cs = hd == 0 ? b0 : hd == 1 ? b1 : hd == 2 ? b2v : b3;
            u32 hv = *(const u32*)(g_xi1 + (size_t)s2 * 32 + (j0 & 31));
            acc0 += bf2f((u16)(hv & 0xffff)) * cs;
            acc1 += bf2f((u16)(hv >> 16)) * cs;
        }
    }
    for (int mk = 32; mk >= 1; mk >>= 1) {
        z0 += __shfl_xor(z0, mk); z1 += __shfl_xor(z1, mk);
        z2 += __shfl_xor(z2, mk); z3 += __shfl_xor(z3, mk);
    }
    float iv = 1.f / ((hd == 0 ? z0 : hd == 1 ? z1 : hd == 2 ? z2 : z3) + 1e-16f);
    ((u32*)g_agg1)[((size_t)n * 128 + j0) >> 1] =
        (u32)f2bf(acc0 * iv) | ((u32)f2bf(acc1 * iv) << 16);
}

// ---------------- batch norm ----------------
__global__ __launch_bounds__(256) void k_bnstats() {
    int t = threadIdx.x;
    int j = t & 127;
    int r0 = blockIdx.x * 2 + (t >> 7);
    float s = 0.f, ss = 0.f;
    for (int r = r0; r < NN; r += 500) {
        float v = g_xbuf[(size_t)r * 128 + j];
        s += v; ss += v * v;
    }
    atomicAdd(&g_bnsum[j], s);
    atomicAdd(&g_bnsumsq[j], ss);
}
__global__ void k_bnfin(const void* gamma, const void* beta) {
    int isbf = g_flag;
    int j = threadIdx.x;  // 128
    float mu = g_bnsum[j] * (1.f / NN);
    float var = fmaxf(g_bnsumsq[j] * (1.f / NN) - mu * mu, 0.f);
    float rstd = rsqrtf(var + 1e-5f);
    float sc = ldf(gamma, j, isbf) * rstd;
    g_bnscale[j] = sc;
    g_bnshift[j] = ldf(beta, j, isbf) - mu * sc;
}

// ---------------- fused softmax + aggregation, layer 2 (128-wide xi2) -----
// agg2[n, h*128+c] = (sum_e exp(a_eh - m_h) * xi2[src_e, c]) / z_h
__global__ __launch_bounds__(256) void k_att2(const int* __restrict__ srcp) {
    int lane = threadIdx.x & 63;
    int n = blockIdx.x * 4 + (threadIdx.x >> 6);
    if (n >= NN) return;
    int st = g_start[n], dg = g_deg[n];
    float m0 = -1e30f, m1 = -1e30f, m2 = -1e30f, m3 = -1e30f;
    for (int i = lane; i < dg; i += 64) {
        int e = g_eidx[st + i];
        float4 a = *(const float4*)(g_alpha + 4 * (size_t)e);
        m0 = fmaxf(m0, a.x); m1 = fmaxf(m1, a.y);
        m2 = fmaxf(m2, a.z); m3 = fmaxf(m3, a.w);
    }
    for (int mk = 32; mk >= 1; mk >>= 1) {
        m0 = fmaxf(m0, __shfl_xor(m0, mk)); m1 = fmaxf(m1, __shfl_xor(m1, mk));
        m2 = fmaxf(m2, __shfl_xor(m2, mk)); m3 = fmaxf(m3, __shfl_xor(m3, mk));
    }
    if (m0 < -1e29f) m0 = 0.f;
    if (m1 < -1e29f) m1 = 0.f;
    if (m2 < -1e29f) m2 = 0.f;
    if (m3 < -1e29f) m3 = 0.f;
    int c0 = 2 * lane;
    float z0 = 0.f, z1 = 0.f, z2 = 0.f, z3 = 0.f;
    float a00 = 0.f, a01 = 0.f, a10 = 0.f, a11 = 0.f;
    float a20 = 0.f, a21 = 0.f, a30 = 0.f, a31 = 0.f;
    for (int base = 0; base < dg; base += 64) {
        int i = base + lane;
        int sidx = 0; float c0f = 0.f, c1f = 0.f, c2f = 0.f, c3f = 0.f;
        if (i < dg) {
            int e = g_eidx[st + i];
            float4 a = *(const float4*)(g_alpha + 4 * (size_t)e);
            sidx = srcp[e];
            c0f = expf(a.x - m0); c1f = expf(a.y - m1);
            c2f = expf(a.z - m2); c3f = expf(a.w - m3);
            z0 += c0f; z1 += c1f; z2 += c2f; z3 += c3f;
        }
        int cnt = min(64, dg - base);
        for (int jj = 0; jj < cnt; jj++) {
            int s2 = __shfl(sidx, jj);
            float b0 = __shfl(c0f, jj), b1 = __shfl(c1f, jj);
            float b2v = __shfl(c2f, jj), b3 = __shfl(c3f, jj);
            u32 hv = *(const u32*)(g_xi2 + (size_t)s2 * 128 + c0);
            float lo = bf2f((u16)(hv & 0xffff)), hi = bf2f((u16)(hv >> 16));
            a00 += lo * b0;  a01 += hi * b0;
            a10 += lo * b1;  a11 += hi * b1;
            a20 += lo * b2v; a21 += hi * b2v;
            a30 += lo * b3;  a31 += hi * b3;
        }
    }
    for (int mk = 32; mk >= 1; mk >>= 1) {
        z0 += __shfl_xor(z0, mk); z1 += __shfl_xor(z1, mk);
        z2 += __shfl_xor(z2, mk); z3 += __shfl_xor(z3, mk);
    }
    float iv0 = 1.f / (z0 + 1e-16f), iv1 = 1.f / (z1 + 1e-16f);
    float iv2 = 1.f / (z2 + 1e-16f), iv3 = 1.f / (z3 + 1e-16f);
    u32* out = (u32*)g_agg2 + (((size_t)n * 512 + c0) >> 1);
    out[0]   = (u32)f2bf(a00 * iv0) | ((u32)f2bf(a01 * iv0) << 16);
    out[64]  = (u32)f2bf(a10 * iv1) | ((u32)f2bf(a11 * iv1) << 16);
    out[128] = (u32)f2bf(a20 * iv2) | ((u32)f2bf(a21 * iv2) << 16);
    out[192] = (u32)f2bf(a30 * iv3) | ((u32)f2bf(a31 * iv3) << 16);
}

// ---------------- launcher ----------------
extern "C" void kernel_launch(void* const* d_in, const int* in_sizes, int n_in,
                              void* d_out, int out_size, void* d_ws, size_t ws_size,
                              hipStream_t stream) {
    const void* x     = d_in[0];
    const int* ei     = (const int*)d_in[1];
    const int* ntype  = (const int*)d_in[2];
    const void* eattr = d_in[3];
    const int* etype  = (const int*)d_in[4];
    const void* ne1   = d_in[5];
    const void* w1    = d_in[6];
    const void* we1   = d_in[7];
    const void* asrc1 = d_in[8];
    const void* adst1 = d_in[9];
    const void* aedge1= d_in[10];
    const void* ee1   = d_in[11];
    const void* wres1 = d_in[12];
    const void* b1    = d_in[13];
    const void* gamma = d_in[14];
    const void* beta  = d_in[15];
    const void* ne2   = d_in[16];
    const void* w2    = d_in[17];
    const void* we2   = d_in[18];
    const void* asrc2 = d_in[19];
    const void* adst2 = d_in[20];
    const void* aedge2= d_in[21];
    const void* ee2   = d_in[22];
    const void* wres2 = d_in[23];
    const void* b2    = d_in[24];
    (void)in_sizes; (void)n_in; (void)out_size; (void)d_ws; (void)ws_size;

    const int* srcp = ei;
    const int* dstp = ei + NE;

    k_zero<<<196, 256, 0, stream>>>((const u16*)x);
    k_prep<<<112, 256, 0, stream>>>(we1, aedge1, we2, aedge2,
                                    w1, asrc1, adst1, w2, asrc2, adst2);
    k_prep2<<<2, 256, 0, stream>>>(ee1, ee2);
    k_deg<<<1563, 256, 0, stream>>>(dstp);
    k_start<<<196, 256, 0, stream>>>();
    k_scatter<<<1563, 256, 0, stream>>>(dstp);

    // ---- edge logits (pure stream over eattr, both layers) ----
    k_edgemm<<<(NE + 255) / 256, 256, 0, stream>>>(etype, eattr);

    // ---- layer 1 ----
    k_buildA1<<<(MPAD * 32 + 255) / 256, 256, 0, stream>>>(x, ntype, ne1);
    k_buildB1all<<<320, 128, 0, stream>>>(ne1, w1, wres1, b1);
    k_gemm<64, 64, 1><<<dim3(MPAD / 64, 3), 256, 0, stream>>>(nullptr);
    k_edgeadd<<<1563, 256, 0, stream>>>(srcp, dstp, 1);
    k_att1<<<12500, 256, 0, stream>>>(srcp);
    k_gemm<128, 128, 3><<<dim3(MPAD / 64, 2), 256, 0, stream>>>(nullptr);

    // ---- batch norm ----
    k_bnstats<<<250, 256, 0, stream>>>();
    k_bnfin<<<1, 128, 0, stream>>>(gamma, beta);

    // ---- layer 2 ----
    k_xi2<<<12500, 256, 0, stream>>>(ntype, ne2);   // + A2 onehot tail
    k_buildB2all<<<320, 256, 0, stream>>>(ne2, w2, wres2, b2);
    k_gemm<160, 160, 2><<<dim3(MPAD / 64, 3), 256, 0, stream>>>(nullptr);
    k_edgeadd<<<1563, 256, 0, stream>>>(srcp, dstp, 2);
    k_att2<<<12500, 256, 0, stream>>>(srcp);
    k_gemm<512, 128, 4><<<dim3(MPAD / 64, 2), 256, 0, stream>>>(d_out);
}